// Round 3
// baseline (1162.367 us; speedup 1.0000x reference)
//
#include <hip/hip_runtime.h>
#include <math.h>

// PointcloudToVoxels: B=4 batches, C channels (32), N points (200k),
// 64x64x64 grid, V = 262144 voxels.
// Output layout: [B,C,V] voxeldata (float32) then [B,1,V] occupancy (float32).

#define GW 64
#define GL 64
#define GH 64
#define GV (GW * GL * GH)   // 262144 = 2^18
#define NB 4
#define MIN_PTS 10

// Monotonic order-preserving float32 <-> uint32 encoding.
// All finite floats encode to > 0, so a 0-initialized buffer acts as -inf
// under unsigned atomicMax.
__device__ __forceinline__ unsigned enc_f32(float f) {
    unsigned u = __float_as_uint(f);
    return (u & 0x80000000u) ? ~u : (u | 0x80000000u);
}
__device__ __forceinline__ float dec_f32(unsigned u) {
    return (u & 0x80000000u) ? __uint_as_float(u & 0x7FFFFFFFu)
                             : __uint_as_float(~u);
}

// Binning that bit-matches XLA's compilation of floor(x/0.05 + 0.5):
// XLA rewrites x / const -> x * (1/const) with the reciprocal folded at
// compile time; fl32(1/0.05f) == 20.0f exactly. __fmul_rn/__fadd_rn forbid
// FMA contraction so we reproduce mul-then-add-then-floor exactly.
// [R0: f32 correctly-rounded div -> absmax 3.10; R2: f64 div -> 3.23 --
//  both wrong on bin-edge points, pointing at the reciprocal-mul form.]
__device__ __forceinline__ int bin_coord(float x) {
    float m = __fmul_rn(x, 20.0f);
    float r = __fadd_rn(m, 0.5f);
    return (int)floorf(r);
}

// Zero-init the encoded-max buffer (d_out voxeldata region) and the counts
// buffer (d_ws). Vectorized 16B stores.
__global__ void init_kernel(uint4* __restrict__ data4, uint4* __restrict__ cnt4,
                            int nData4, int nCnt4) {
    int i = blockIdx.x * blockDim.x + threadIdx.x;
    uint4 z = make_uint4(0u, 0u, 0u, 0u);
    if (i < nData4) {
        data4[i] = z;
    } else if (i < nData4 + nCnt4) {
        cnt4[i - nData4] = z;
    }
}

// One thread per (batch, point): compute voxel, bump count, atomicMax each
// channel's encoded value. Attribute reads are coalesced across the wave
// (consecutive n); atomic targets are inherently scattered.
__global__ void scatter_kernel(const float* __restrict__ coords,
                               const float* __restrict__ attrs,
                               unsigned* __restrict__ bits,
                               int* __restrict__ counts,
                               int N, int C) {
    int n = blockIdx.x * blockDim.x + threadIdx.x;
    int b = blockIdx.y;
    if (n >= N) return;

    const float* pc = coords + (size_t)b * 3 * N;
    int ix = bin_coord(pc[n]);
    int iy = bin_coord(pc[n + N]);
    int iz = bin_coord(pc[n + 2 * N]);
    if ((unsigned)ix >= (unsigned)GW || (unsigned)iy >= (unsigned)GL ||
        (unsigned)iz >= (unsigned)GH)
        return;

    int v = (ix << 12) | (iy << 6) | iz;
    atomicAdd(&counts[b * GV + v], 1);

    const float* pa = attrs + (size_t)b * C * N + n;
    unsigned* pb = bits + (size_t)b * C * GV + v;
#pragma unroll 8
    for (int c = 0; c < C; ++c) {
        unsigned e = enc_f32(pa[(size_t)c * N]);
        atomicMax(&pb[(size_t)c * GV], e);
    }
}

// Decode in place: voxeldata[idx] = count>0 ? dec(bits) : 0 ; occupancy.
__global__ void finalize_kernel(unsigned* __restrict__ data,
                                const int* __restrict__ counts,
                                float* __restrict__ occ,
                                int C) {
    int i = blockIdx.x * blockDim.x + threadIdx.x;
    int nData4 = NB * C * GV / 4;
    int nOcc4 = NB * GV / 4;
    if (i < nData4) {
        int idx = i << 2;
        int v = idx & (GV - 1);
        int b = idx / (C * GV);
        int4 cnt = *(const int4*)&counts[b * GV + v];
        uint4 u = *(const uint4*)&data[idx];
        float4 r;
        r.x = cnt.x > 0 ? dec_f32(u.x) : 0.0f;
        r.y = cnt.y > 0 ? dec_f32(u.y) : 0.0f;
        r.z = cnt.z > 0 ? dec_f32(u.z) : 0.0f;
        r.w = cnt.w > 0 ? dec_f32(u.w) : 0.0f;
        *(float4*)&data[idx] = r;
    } else if (i < nData4 + nOcc4) {
        int j = (i - nData4) << 2;
        int4 cnt = *(const int4*)&counts[j];
        float4 r;
        r.x = cnt.x >= MIN_PTS ? 1.0f : 0.0f;
        r.y = cnt.y >= MIN_PTS ? 1.0f : 0.0f;
        r.z = cnt.z >= MIN_PTS ? 1.0f : 0.0f;
        r.w = cnt.w >= MIN_PTS ? 1.0f : 0.0f;
        *(float4*)&occ[j] = r;
    }
}

extern "C" void kernel_launch(void* const* d_in, const int* in_sizes, int n_in,
                              void* d_out, int out_size, void* d_ws, size_t ws_size,
                              hipStream_t stream) {
    const float* coords = (const float*)d_in[0];  // [B,3,N]
    const float* attrs  = (const float*)d_in[1];  // [B,C,N]
    int N = in_sizes[0] / (NB * 3);
    int C = in_sizes[1] / (NB * N);

    unsigned* bits = (unsigned*)d_out;                       // [B,C,V] region
    float* occ = (float*)d_out + (size_t)NB * C * GV;        // [B,1,V] region
    int* counts = (int*)d_ws;                                // [B,V] ints (4 MB)

    int nData4 = NB * C * GV / 4;   // 8,388,608
    int nCnt4  = NB * GV / 4;       // 262,144 (also nOcc4)

    int initTotal = nData4 + nCnt4;
    init_kernel<<<(initTotal + 255) / 256, 256, 0, stream>>>(
        (uint4*)d_out, (uint4*)d_ws, nData4, nCnt4);

    dim3 sgrid((N + 255) / 256, NB);
    scatter_kernel<<<sgrid, 256, 0, stream>>>(coords, attrs, bits, counts, N, C);

    int finTotal = nData4 + nCnt4;
    finalize_kernel<<<(finTotal + 255) / 256, 256, 0, stream>>>(
        bits, counts, occ, C);
}